// Round 1
// baseline (512.481 us; speedup 1.0000x reference)
//
#include <hip/hip_runtime.h>

#define RAD 40
#define SEG 128
#define EPS 1e-3f

// ---------------------------------------------------------------------------
// K1: vertical sliding box-sum of I, p, I*p, I*I. One thread per column,
// each block covers 256 columns x SEG output rows. Coalesced row reads.
// ---------------------------------------------------------------------------
__global__ __launch_bounds__(256)
void vbox4_kernel(const float* __restrict__ I, const float* __restrict__ p,
                  float* __restrict__ o0, float* __restrict__ o1,
                  float* __restrict__ o2, float* __restrict__ o3,
                  int H, int W, int ncol) {
    int gcol = blockIdx.x * 256 + threadIdx.x;
    if (gcol >= ncol) return;
    int c = gcol / W;
    int x = gcol - c * W;
    const size_t base = (size_t)c * H * W + x;
    int y0 = blockIdx.y * SEG;

    float s0 = 0.f, s1 = 0.f, s2 = 0.f, s3 = 0.f;
    int ylo = y0 - RAD; if (ylo < 0) ylo = 0;
    // prime: rows [ylo, y0+RAD)
    for (int y = ylo; y < y0 + RAD; ++y) {
        float a = I[base + (size_t)y * W];
        float b = p[base + (size_t)y * W];
        s0 += a; s1 += b; s2 += a * b; s3 += a * a;
    }
    for (int y = y0; y < y0 + SEG; ++y) {
        int ya = y + RAD;
        if (ya < H) {
            float a = I[base + (size_t)ya * W];
            float b = p[base + (size_t)ya * W];
            s0 += a; s1 += b; s2 += a * b; s3 += a * a;
        }
        size_t idx = base + (size_t)y * W;
        o0[idx] = s0; o1[idx] = s1; o2[idx] = s2; o3[idx] = s3;
        int ys = y - RAD;
        if (ys >= 0) {
            float a = I[base + (size_t)ys * W];
            float b = p[base + (size_t)ys * W];
            s0 -= a; s1 -= b; s2 -= a * b; s3 -= a * a;
        }
    }
}

// ---------------------------------------------------------------------------
// K3: same, 2 fields (a, b)
// ---------------------------------------------------------------------------
__global__ __launch_bounds__(256)
void vbox2_kernel(const float* __restrict__ ia, const float* __restrict__ ib,
                  float* __restrict__ oa, float* __restrict__ ob,
                  int H, int W, int ncol) {
    int gcol = blockIdx.x * 256 + threadIdx.x;
    if (gcol >= ncol) return;
    int c = gcol / W;
    int x = gcol - c * W;
    const size_t base = (size_t)c * H * W + x;
    int y0 = blockIdx.y * SEG;

    float s0 = 0.f, s1 = 0.f;
    int ylo = y0 - RAD; if (ylo < 0) ylo = 0;
    for (int y = ylo; y < y0 + RAD; ++y) {
        s0 += ia[base + (size_t)y * W];
        s1 += ib[base + (size_t)y * W];
    }
    for (int y = y0; y < y0 + SEG; ++y) {
        int ya = y + RAD;
        if (ya < H) {
            s0 += ia[base + (size_t)ya * W];
            s1 += ib[base + (size_t)ya * W];
        }
        size_t idx = base + (size_t)y * W;
        oa[idx] = s0; ob[idx] = s1;
        int ys = y - RAD;
        if (ys >= 0) {
            s0 -= ia[base + (size_t)ys * W];
            s1 -= ib[base + (size_t)ys * W];
        }
    }
}

// ---------------------------------------------------------------------------
// Block-wide inclusive prefix scan of a 1024-float LDS array, 256 threads.
// ---------------------------------------------------------------------------
__device__ __forceinline__ float wave_incl_scan(float v, int lane) {
    #pragma unroll
    for (int d = 1; d < 64; d <<= 1) {
        float n = __shfl_up(v, d, 64);
        if (lane >= d) v += n;
    }
    return v;
}

__device__ __forceinline__ void block_scan_1024(float* s, float* wsum, int tid) {
    int lane = tid & 63, wid = tid >> 6;
    float v0 = s[4 * tid], v1 = s[4 * tid + 1], v2 = s[4 * tid + 2], v3 = s[4 * tid + 3];
    float l1 = v0 + v1, l2 = l1 + v2, l3 = l2 + v3;
    float sc = wave_incl_scan(l3, lane);
    __syncthreads();                 // previous consumers of wsum are done
    if (lane == 63) wsum[wid] = sc;
    __syncthreads();
    float wofs = 0.f;
    #pragma unroll
    for (int wI = 0; wI < 3; ++wI) if (wI < wid) wofs += wsum[wI];
    float excl = wofs + sc - l3;     // exclusive prefix of this thread's 4 elems
    s[4 * tid]     = excl + v0;
    s[4 * tid + 1] = excl + l1;
    s[4 * tid + 2] = excl + l2;
    s[4 * tid + 3] = excl + l3;
    __syncthreads();
}

// ---------------------------------------------------------------------------
// K2: horizontal box-sum of the 4 vertically-summed fields -> a, b.
// One block per (channel,row). In-place into f0,f1 (row staged in LDS first).
// ---------------------------------------------------------------------------
__global__ __launch_bounds__(256)
void hbox_ab_kernel(const float* __restrict__ f0, const float* __restrict__ f1,
                    const float* __restrict__ f2, const float* __restrict__ f3,
                    float* __restrict__ oa, float* __restrict__ ob,
                    int H, int W) {
    __shared__ float s0[1024], s1[1024], s2[1024], s3[1024];
    __shared__ float wsum[4];
    int row = blockIdx.x;            // c*H + y
    int y = row & (H - 1);
    size_t base = (size_t)row * W;
    int tid = threadIdx.x;

    #pragma unroll
    for (int j = 0; j < 4; ++j) {
        int i = tid + j * 256;
        s0[i] = f0[base + i];
        s1[i] = f1[base + i];
        s2[i] = f2[base + i];
        s3[i] = f3[base + i];
    }
    __syncthreads();
    block_scan_1024(s0, wsum, tid);
    block_scan_1024(s1, wsum, tid);
    block_scan_1024(s2, wsum, tid);
    block_scan_1024(s3, wsum, tid);

    int cv_hi = y + RAD + 1; if (cv_hi > H) cv_hi = H;
    int cv_lo = y - RAD;     if (cv_lo < 0) cv_lo = 0;
    float cntV = (float)(cv_hi - cv_lo);

    #pragma unroll
    for (int j = 0; j < 4; ++j) {
        int i = tid + j * 256;
        int hi = i + RAD; if (hi > W - 1) hi = W - 1;
        int lo = i - RAD - 1;
        float bI  = s0[hi] - (lo >= 0 ? s0[lo] : 0.f);
        float bp  = s1[hi] - (lo >= 0 ? s1[lo] : 0.f);
        float bIp = s2[hi] - (lo >= 0 ? s2[lo] : 0.f);
        float bII = s3[hi] - (lo >= 0 ? s3[lo] : 0.f);
        int ch_hi = i + RAD + 1; if (ch_hi > W) ch_hi = W;
        int ch_lo = i - RAD;     if (ch_lo < 0) ch_lo = 0;
        float ic = 1.f / (cntV * (float)(ch_hi - ch_lo));
        float mI = bI * ic, mp = bp * ic, mIp = bIp * ic, mII = bII * ic;
        float cov = mIp - mI * mp;
        float var = mII - mI * mI;
        float a = cov / (var + EPS);
        float b = mp - a * mI;
        oa[base + i] = a;
        ob[base + i] = b;
    }
}

// ---------------------------------------------------------------------------
// K4: horizontal box-sum of vsum(a), vsum(b) + epilogue out = mean_a*I + mean_b
// ---------------------------------------------------------------------------
__global__ __launch_bounds__(256)
void hbox_final_kernel(const float* __restrict__ fa, const float* __restrict__ fb,
                       const float* __restrict__ I, float* __restrict__ out,
                       int H, int W) {
    __shared__ float sa[1024], sb[1024];
    __shared__ float wsum[4];
    int row = blockIdx.x;
    int y = row & (H - 1);
    size_t base = (size_t)row * W;
    int tid = threadIdx.x;

    #pragma unroll
    for (int j = 0; j < 4; ++j) {
        int i = tid + j * 256;
        sa[i] = fa[base + i];
        sb[i] = fb[base + i];
    }
    __syncthreads();
    block_scan_1024(sa, wsum, tid);
    block_scan_1024(sb, wsum, tid);

    int cv_hi = y + RAD + 1; if (cv_hi > H) cv_hi = H;
    int cv_lo = y - RAD;     if (cv_lo < 0) cv_lo = 0;
    float cntV = (float)(cv_hi - cv_lo);

    #pragma unroll
    for (int j = 0; j < 4; ++j) {
        int i = tid + j * 256;
        int hi = i + RAD; if (hi > W - 1) hi = W - 1;
        int lo = i - RAD - 1;
        float ba = sa[hi] - (lo >= 0 ? sa[lo] : 0.f);
        float bb = sb[hi] - (lo >= 0 ? sb[lo] : 0.f);
        int ch_hi = i + RAD + 1; if (ch_hi > W) ch_hi = W;
        int ch_lo = i - RAD;     if (ch_lo < 0) ch_lo = 0;
        float ic = 1.f / (cntV * (float)(ch_hi - ch_lo));
        out[base + i] = (ba * ic) * I[base + i] + (bb * ic);
    }
}

extern "C" void kernel_launch(void* const* d_in, const int* in_sizes, int n_in,
                              void* d_out, int out_size, void* d_ws, size_t ws_size,
                              hipStream_t stream) {
    const float* I = (const float*)d_in[0];
    const float* p = (const float*)d_in[1];
    float* out = (float*)d_out;

    const int H = 1024, W = 1024;
    const int N = in_sizes[0];       // B*C*H*W
    const int BC = N / (H * W);

    // Workspace layout: 3 fields in d_ws (3*N floats = 151 MB), d_out is field 3.
    float* f0 = (float*)d_ws;
    float* f1 = f0 + N;
    float* f2 = f1 + N;
    float* f3 = out;

    const int ncol = BC * W;
    dim3 vgrid((ncol + 255) / 256, H / SEG);

    // K1: vertical box-sums of I, p, I*p, I*I
    vbox4_kernel<<<vgrid, 256, 0, stream>>>(I, p, f0, f1, f2, f3, H, W, ncol);
    // K2: horizontal box-sums -> a (f0), b (f1), in place
    hbox_ab_kernel<<<dim3(BC * H), 256, 0, stream>>>(f0, f1, f2, f3, f0, f1, H, W);
    // K3: vertical box-sums of a, b -> f2, f3
    vbox2_kernel<<<vgrid, 256, 0, stream>>>(f0, f1, f2, f3, H, W, ncol);
    // K4: horizontal box-sums + epilogue -> out
    hbox_final_kernel<<<dim3(BC * H), 256, 0, stream>>>(f2, f3, I, out, H, W);
}

// Round 2
// 367.861 us; speedup vs baseline: 1.3931x; 1.3931x over previous
//
#include <hip/hip_runtime.h>

#define RAD 40
#define SEG 64
#define EPS 1e-3f
#define PAD(e) ((e) + ((e) >> 5))   // LDS padding: +1 slot per 32 elems

// ---------------------------------------------------------------------------
// K1: vertical sliding box-sum of I, p, I*p, I*I. float2 = 2 columns/thread.
// Fast path (no boundary branches) for interior y-segments.
// ---------------------------------------------------------------------------
__global__ __launch_bounds__(256)
void vbox4_kernel(const float2* __restrict__ I, const float2* __restrict__ p,
                  float2* __restrict__ o0, float2* __restrict__ o1,
                  float2* __restrict__ o2, float2* __restrict__ o3,
                  int H, int Wv, int nq) {
    int gq = blockIdx.x * 256 + threadIdx.x;
    if (gq >= nq) return;
    int c = gq / Wv;
    int x = gq - c * Wv;
    const size_t base = (size_t)c * H * Wv + x;
    int y0 = blockIdx.y * SEG;

    float s0x = 0.f, s0y = 0.f, s1x = 0.f, s1y = 0.f;
    float s2x = 0.f, s2y = 0.f, s3x = 0.f, s3y = 0.f;

    int ylo = y0 - RAD; if (ylo < 0) ylo = 0;
    #pragma unroll 4
    for (int y = ylo; y < y0 + RAD; ++y) {
        float2 a = I[base + (size_t)y * Wv];
        float2 b = p[base + (size_t)y * Wv];
        s0x += a.x; s0y += a.y; s1x += b.x; s1y += b.y;
        s2x += a.x * b.x; s2y += a.y * b.y;
        s3x += a.x * a.x; s3y += a.y * a.y;
    }

    if (y0 >= RAD && y0 + SEG + RAD <= H) {
        // interior: no boundary checks
        #pragma unroll 4
        for (int y = y0; y < y0 + SEG; ++y) {
            float2 a = I[base + (size_t)(y + RAD) * Wv];
            float2 b = p[base + (size_t)(y + RAD) * Wv];
            s0x += a.x; s0y += a.y; s1x += b.x; s1y += b.y;
            s2x += a.x * b.x; s2y += a.y * b.y;
            s3x += a.x * a.x; s3y += a.y * a.y;
            size_t idx = base + (size_t)y * Wv;
            o0[idx] = make_float2(s0x, s0y);
            o1[idx] = make_float2(s1x, s1y);
            o2[idx] = make_float2(s2x, s2y);
            o3[idx] = make_float2(s3x, s3y);
            float2 as = I[base + (size_t)(y - RAD) * Wv];
            float2 bs = p[base + (size_t)(y - RAD) * Wv];
            s0x -= as.x; s0y -= as.y; s1x -= bs.x; s1y -= bs.y;
            s2x -= as.x * bs.x; s2y -= as.y * bs.y;
            s3x -= as.x * as.x; s3y -= as.y * as.y;
        }
    } else {
        for (int y = y0; y < y0 + SEG; ++y) {
            int ya = y + RAD;
            if (ya < H) {
                float2 a = I[base + (size_t)ya * Wv];
                float2 b = p[base + (size_t)ya * Wv];
                s0x += a.x; s0y += a.y; s1x += b.x; s1y += b.y;
                s2x += a.x * b.x; s2y += a.y * b.y;
                s3x += a.x * a.x; s3y += a.y * a.y;
            }
            size_t idx = base + (size_t)y * Wv;
            o0[idx] = make_float2(s0x, s0y);
            o1[idx] = make_float2(s1x, s1y);
            o2[idx] = make_float2(s2x, s2y);
            o3[idx] = make_float2(s3x, s3y);
            int ys = y - RAD;
            if (ys >= 0) {
                float2 as = I[base + (size_t)ys * Wv];
                float2 bs = p[base + (size_t)ys * Wv];
                s0x -= as.x; s0y -= as.y; s1x -= bs.x; s1y -= bs.y;
                s2x -= as.x * bs.x; s2y -= as.y * bs.y;
                s3x -= as.x * as.x; s3y -= as.y * as.y;
            }
        }
    }
}

// ---------------------------------------------------------------------------
// K3: vertical sliding box-sum of a, b (float2)
// ---------------------------------------------------------------------------
__global__ __launch_bounds__(256)
void vbox2_kernel(const float2* __restrict__ ia, const float2* __restrict__ ib,
                  float2* __restrict__ oa, float2* __restrict__ ob,
                  int H, int Wv, int nq) {
    int gq = blockIdx.x * 256 + threadIdx.x;
    if (gq >= nq) return;
    int c = gq / Wv;
    int x = gq - c * Wv;
    const size_t base = (size_t)c * H * Wv + x;
    int y0 = blockIdx.y * SEG;

    float s0x = 0.f, s0y = 0.f, s1x = 0.f, s1y = 0.f;
    int ylo = y0 - RAD; if (ylo < 0) ylo = 0;
    #pragma unroll 4
    for (int y = ylo; y < y0 + RAD; ++y) {
        float2 a = ia[base + (size_t)y * Wv];
        float2 b = ib[base + (size_t)y * Wv];
        s0x += a.x; s0y += a.y; s1x += b.x; s1y += b.y;
    }

    if (y0 >= RAD && y0 + SEG + RAD <= H) {
        #pragma unroll 4
        for (int y = y0; y < y0 + SEG; ++y) {
            float2 a = ia[base + (size_t)(y + RAD) * Wv];
            float2 b = ib[base + (size_t)(y + RAD) * Wv];
            s0x += a.x; s0y += a.y; s1x += b.x; s1y += b.y;
            size_t idx = base + (size_t)y * Wv;
            oa[idx] = make_float2(s0x, s0y);
            ob[idx] = make_float2(s1x, s1y);
            float2 as = ia[base + (size_t)(y - RAD) * Wv];
            float2 bs = ib[base + (size_t)(y - RAD) * Wv];
            s0x -= as.x; s0y -= as.y; s1x -= bs.x; s1y -= bs.y;
        }
    } else {
        for (int y = y0; y < y0 + SEG; ++y) {
            int ya = y + RAD;
            if (ya < H) {
                float2 a = ia[base + (size_t)ya * Wv];
                float2 b = ib[base + (size_t)ya * Wv];
                s0x += a.x; s0y += a.y; s1x += b.x; s1y += b.y;
            }
            size_t idx = base + (size_t)y * Wv;
            oa[idx] = make_float2(s0x, s0y);
            ob[idx] = make_float2(s1x, s1y);
            int ys = y - RAD;
            if (ys >= 0) {
                float2 as = ia[base + (size_t)ys * Wv];
                float2 bs = ib[base + (size_t)ys * Wv];
                s0x -= as.x; s0y -= as.y; s1x -= bs.x; s1y -= bs.y;
            }
        }
    }
}

// ---------------------------------------------------------------------------
// K2: horizontal box-sum of 4 fields -> a, b. One block per (channel,row).
// Fused 4-field scan: 3 barriers total, padded LDS.
// ---------------------------------------------------------------------------
__global__ __launch_bounds__(256)
void hbox_ab_kernel(const float* __restrict__ f0, const float* __restrict__ f1,
                    const float* __restrict__ f2, const float* __restrict__ f3,
                    float* __restrict__ oa, float* __restrict__ ob,
                    int H, int W) {
    __shared__ float s0[1056], s1[1056], s2[1056], s3[1056];
    __shared__ float wsum[4][4];   // [wave][field]
    int row = blockIdx.x;
    int y = row & (H - 1);
    size_t base = (size_t)row * W;
    int tid = threadIdx.x, lane = tid & 63, wid = tid >> 6;

    #pragma unroll
    for (int j = 0; j < 4; ++j) {
        int i = tid + j * 256;
        s0[PAD(i)] = f0[base + i];
        s1[PAD(i)] = f1[base + i];
        s2[PAD(i)] = f2[base + i];
        s3[PAD(i)] = f3[base + i];
    }
    __syncthreads();

    // each thread owns 4 contiguous elems per field; cumulative within thread
    float c0[4], c1[4], c2[4], c3[4];
    {
        float r0 = 0.f, r1 = 0.f, r2 = 0.f, r3 = 0.f;
        #pragma unroll
        for (int k = 0; k < 4; ++k) {
            int e = PAD(4 * tid + k);
            r0 += s0[e]; r1 += s1[e]; r2 += s2[e]; r3 += s3[e];
            c0[k] = r0; c1[k] = r1; c2[k] = r2; c3[k] = r3;
        }
    }
    // interleaved 4-field wave inclusive scan of thread totals
    float t0 = c0[3], t1 = c1[3], t2 = c2[3], t3 = c3[3];
    float u0 = t0, u1 = t1, u2 = t2, u3 = t3;
    #pragma unroll
    for (int d = 1; d < 64; d <<= 1) {
        float n0 = __shfl_up(u0, d, 64);
        float n1 = __shfl_up(u1, d, 64);
        float n2 = __shfl_up(u2, d, 64);
        float n3 = __shfl_up(u3, d, 64);
        if (lane >= d) { u0 += n0; u1 += n1; u2 += n2; u3 += n3; }
    }
    if (lane == 63) { wsum[wid][0] = u0; wsum[wid][1] = u1; wsum[wid][2] = u2; wsum[wid][3] = u3; }
    __syncthreads();
    float w0 = 0.f, w1 = 0.f, w2 = 0.f, w3 = 0.f;
    #pragma unroll
    for (int w = 0; w < 3; ++w)
        if (w < wid) { w0 += wsum[w][0]; w1 += wsum[w][1]; w2 += wsum[w][2]; w3 += wsum[w][3]; }
    float e0 = w0 + u0 - t0, e1 = w1 + u1 - t1, e2 = w2 + u2 - t2, e3 = w3 + u3 - t3;
    #pragma unroll
    for (int k = 0; k < 4; ++k) {
        int e = PAD(4 * tid + k);
        s0[e] = e0 + c0[k]; s1[e] = e1 + c1[k]; s2[e] = e2 + c2[k]; s3[e] = e3 + c3[k];
    }
    __syncthreads();

    int cv_hi = y + RAD + 1; if (cv_hi > H) cv_hi = H;
    int cv_lo = y - RAD;     if (cv_lo < 0) cv_lo = 0;
    float cntV = (float)(cv_hi - cv_lo);

    #pragma unroll
    for (int j = 0; j < 4; ++j) {
        int i = tid + j * 256;
        int hi = i + RAD; if (hi > W - 1) hi = W - 1;
        hi = PAD(hi);
        int lo = i - RAD - 1;
        int lop = PAD(lo >= 0 ? lo : 0);
        float m = (lo >= 0) ? 1.f : 0.f;
        float bI  = s0[hi] - m * s0[lop];
        float bp  = s1[hi] - m * s1[lop];
        float bIp = s2[hi] - m * s2[lop];
        float bII = s3[hi] - m * s3[lop];
        int ch_hi = i + RAD + 1; if (ch_hi > W) ch_hi = W;
        int ch_lo = i - RAD;     if (ch_lo < 0) ch_lo = 0;
        float ic = 1.f / (cntV * (float)(ch_hi - ch_lo));
        float mI = bI * ic, mp = bp * ic, mIp = bIp * ic, mII = bII * ic;
        float cov = mIp - mI * mp;
        float var = mII - mI * mI;
        float a = cov / (var + EPS);
        float b = mp - a * mI;
        oa[base + i] = a;
        ob[base + i] = b;
    }
}

// ---------------------------------------------------------------------------
// K4: horizontal box-sum of vsum(a), vsum(b) + epilogue out = mean_a*I + mean_b
// ---------------------------------------------------------------------------
__global__ __launch_bounds__(256)
void hbox_final_kernel(const float* __restrict__ fa, const float* __restrict__ fb,
                       const float* __restrict__ I, float* __restrict__ out,
                       int H, int W) {
    __shared__ float sa[1056], sb[1056];
    __shared__ float wsum[4][2];
    int row = blockIdx.x;
    int y = row & (H - 1);
    size_t base = (size_t)row * W;
    int tid = threadIdx.x, lane = tid & 63, wid = tid >> 6;

    #pragma unroll
    for (int j = 0; j < 4; ++j) {
        int i = tid + j * 256;
        sa[PAD(i)] = fa[base + i];
        sb[PAD(i)] = fb[base + i];
    }
    __syncthreads();

    float ca[4], cb[4];
    {
        float ra = 0.f, rb = 0.f;
        #pragma unroll
        for (int k = 0; k < 4; ++k) {
            int e = PAD(4 * tid + k);
            ra += sa[e]; rb += sb[e];
            ca[k] = ra; cb[k] = rb;
        }
    }
    float ta = ca[3], tb = cb[3];
    float ua = ta, ub = tb;
    #pragma unroll
    for (int d = 1; d < 64; d <<= 1) {
        float na = __shfl_up(ua, d, 64);
        float nb = __shfl_up(ub, d, 64);
        if (lane >= d) { ua += na; ub += nb; }
    }
    if (lane == 63) { wsum[wid][0] = ua; wsum[wid][1] = ub; }
    __syncthreads();
    float wa = 0.f, wb = 0.f;
    #pragma unroll
    for (int w = 0; w < 3; ++w)
        if (w < wid) { wa += wsum[w][0]; wb += wsum[w][1]; }
    float ea = wa + ua - ta, eb = wb + ub - tb;
    #pragma unroll
    for (int k = 0; k < 4; ++k) {
        int e = PAD(4 * tid + k);
        sa[e] = ea + ca[k]; sb[e] = eb + cb[k];
    }
    __syncthreads();

    int cv_hi = y + RAD + 1; if (cv_hi > H) cv_hi = H;
    int cv_lo = y - RAD;     if (cv_lo < 0) cv_lo = 0;
    float cntV = (float)(cv_hi - cv_lo);

    #pragma unroll
    for (int j = 0; j < 4; ++j) {
        int i = tid + j * 256;
        int hi = i + RAD; if (hi > W - 1) hi = W - 1;
        hi = PAD(hi);
        int lo = i - RAD - 1;
        int lop = PAD(lo >= 0 ? lo : 0);
        float m = (lo >= 0) ? 1.f : 0.f;
        float ba = sa[hi] - m * sa[lop];
        float bb = sb[hi] - m * sb[lop];
        int ch_hi = i + RAD + 1; if (ch_hi > W) ch_hi = W;
        int ch_lo = i - RAD;     if (ch_lo < 0) ch_lo = 0;
        float ic = 1.f / (cntV * (float)(ch_hi - ch_lo));
        out[base + i] = (ba * ic) * I[base + i] + (bb * ic);
    }
}

extern "C" void kernel_launch(void* const* d_in, const int* in_sizes, int n_in,
                              void* d_out, int out_size, void* d_ws, size_t ws_size,
                              hipStream_t stream) {
    const float* I = (const float*)d_in[0];
    const float* p = (const float*)d_in[1];
    float* out = (float*)d_out;

    const int H = 1024, W = 1024;
    const int N = in_sizes[0];       // B*C*H*W
    const int BC = N / (H * W);

    float* f0 = (float*)d_ws;
    float* f1 = f0 + N;
    float* f2 = f1 + N;
    float* f3 = out;                 // d_out doubles as field 3 (fully rewritten)

    const int Wv = W / 2;            // float2 columns
    const int nq = BC * Wv;
    dim3 vgrid((nq + 255) / 256, H / SEG);

    vbox4_kernel<<<vgrid, 256, 0, stream>>>((const float2*)I, (const float2*)p,
                                            (float2*)f0, (float2*)f1, (float2*)f2, (float2*)f3,
                                            H, Wv, nq);
    hbox_ab_kernel<<<dim3(BC * H), 256, 0, stream>>>(f0, f1, f2, f3, f0, f1, H, W);
    vbox2_kernel<<<vgrid, 256, 0, stream>>>((const float2*)f0, (const float2*)f1,
                                            (float2*)f2, (float2*)f3, H, Wv, nq);
    hbox_final_kernel<<<dim3(BC * H), 256, 0, stream>>>(f2, f3, I, out, H, W);
}

// Round 3
// 338.308 us; speedup vs baseline: 1.5148x; 1.0874x over previous
//
#include <hip/hip_runtime.h>

#define RAD 40
#define SEGF 16                     // output rows per block strip
#define EPS 1e-3f
#define PAD(e) ((e) + ((e) >> 5))   // LDS padding: +1 slot per 32 elems

// ---------------------------------------------------------------------------
// K_A: fused vertical slide + horizontal scan.  I,p -> a,b (AoS float2).
// Block = 256 threads = 1024 columns (4/thread), SEGF rows, 2 barriers/row.
// ---------------------------------------------------------------------------
__global__ __launch_bounds__(256)
void fused_ab_kernel(const float* __restrict__ I, const float* __restrict__ p,
                     float* __restrict__ ab, int H, int W, int nstrip) {
    __shared__ float s0[1056], s1[1056], s2[1056], s3[1056];
    __shared__ float wsum[4][4];
    const int tid = threadIdx.x, lane = tid & 63, wid = tid >> 6;
    const int c = blockIdx.x / nstrip;
    const int y0 = (blockIdx.x - c * nstrip) * SEGF;
    const size_t plane = (size_t)c * H * W;

    float v0[4] = {0,0,0,0}, v1[4] = {0,0,0,0};
    float v2[4] = {0,0,0,0}, v3[4] = {0,0,0,0};

    // prime rows [y0-RAD, y0+RAD)
    int yp0 = y0 - RAD; if (yp0 < 0) yp0 = 0;
    int yp1 = y0 + RAD; if (yp1 > H) yp1 = H;
    #pragma unroll 4
    for (int y = yp0; y < yp1; ++y) {
        float4 a = ((const float4*)(I + plane + (size_t)y * W))[tid];
        float4 b = ((const float4*)(p + plane + (size_t)y * W))[tid];
        v0[0] += a.x; v0[1] += a.y; v0[2] += a.z; v0[3] += a.w;
        v1[0] += b.x; v1[1] += b.y; v1[2] += b.z; v1[3] += b.w;
        v2[0] += a.x*b.x; v2[1] += a.y*b.y; v2[2] += a.z*b.z; v2[3] += a.w*b.w;
        v3[0] += a.x*a.x; v3[1] += a.y*a.y; v3[2] += a.z*a.z; v3[3] += a.w*a.w;
    }

    // prefetched add-row
    float4 pa, pb;
    if (y0 + RAD < H) {
        pa = ((const float4*)(I + plane + (size_t)(y0 + RAD) * W))[tid];
        pb = ((const float4*)(p + plane + (size_t)(y0 + RAD) * W))[tid];
    }

    for (int y = y0; y < y0 + SEGF; ++y) {
        if (y + RAD < H) {
            v0[0] += pa.x; v0[1] += pa.y; v0[2] += pa.z; v0[3] += pa.w;
            v1[0] += pb.x; v1[1] += pb.y; v1[2] += pb.z; v1[3] += pb.w;
            v2[0] += pa.x*pb.x; v2[1] += pa.y*pb.y; v2[2] += pa.z*pb.z; v2[3] += pa.w*pb.w;
            v3[0] += pa.x*pa.x; v3[1] += pa.y*pa.y; v3[2] += pa.z*pa.z; v3[3] += pa.w*pa.w;
        }
        // issue next add-row + sub-row loads now; consumed after the scan
        const int yn = y + 1 + RAD;
        const bool nh = (yn < H) && (y + 1 < y0 + SEGF);
        float4 na, nb;
        if (nh) {
            na = ((const float4*)(I + plane + (size_t)yn * W))[tid];
            nb = ((const float4*)(p + plane + (size_t)yn * W))[tid];
        }
        const int ys = y - RAD;
        float4 sa_, sb_;
        if (ys >= 0) {
            sa_ = ((const float4*)(I + plane + (size_t)ys * W))[tid];
            sb_ = ((const float4*)(p + plane + (size_t)ys * W))[tid];
        }

        // in-thread cumsum of 4 fields
        float c0[4], c1[4], c2[4], c3[4];
        c0[0]=v0[0]; c0[1]=c0[0]+v0[1]; c0[2]=c0[1]+v0[2]; c0[3]=c0[2]+v0[3];
        c1[0]=v1[0]; c1[1]=c1[0]+v1[1]; c1[2]=c1[1]+v1[2]; c1[3]=c1[2]+v1[3];
        c2[0]=v2[0]; c2[1]=c2[0]+v2[1]; c2[2]=c2[1]+v2[2]; c2[3]=c2[2]+v2[3];
        c3[0]=v3[0]; c3[1]=c3[0]+v3[1]; c3[2]=c3[1]+v3[2]; c3[3]=c3[2]+v3[3];
        float t0=c0[3], t1=c1[3], t2=c2[3], t3=c3[3];
        float u0=t0, u1=t1, u2=t2, u3=t3;
        #pragma unroll
        for (int d = 1; d < 64; d <<= 1) {
            float n0=__shfl_up(u0,d,64), n1=__shfl_up(u1,d,64);
            float n2=__shfl_up(u2,d,64), n3=__shfl_up(u3,d,64);
            if (lane >= d) { u0+=n0; u1+=n1; u2+=n2; u3+=n3; }
        }
        if (lane == 63) { wsum[wid][0]=u0; wsum[wid][1]=u1; wsum[wid][2]=u2; wsum[wid][3]=u3; }
        __syncthreads();   // A: wsum ready; also protects prefix arrays (WAR vs prev row's reads)
        float w0=0.f, w1=0.f, w2=0.f, w3=0.f;
        #pragma unroll
        for (int w = 0; w < 3; ++w)
            if (w < wid) { w0+=wsum[w][0]; w1+=wsum[w][1]; w2+=wsum[w][2]; w3+=wsum[w][3]; }
        float e0=w0+u0-t0, e1=w1+u1-t1, e2=w2+u2-t2, e3=w3+u3-t3;
        #pragma unroll
        for (int k = 0; k < 4; ++k) {
            int e = PAD(4*tid+k);
            s0[e]=e0+c0[k]; s1[e]=e1+c1[k]; s2[e]=e2+c2[k]; s3[e]=e3+c3[k];
        }
        __syncthreads();   // B: prefixes ready; also protects wsum (WAR vs next row's writes)

        int cv_hi = y + RAD + 1; if (cv_hi > H) cv_hi = H;
        int cv_lo = y - RAD;     if (cv_lo < 0) cv_lo = 0;
        float cntV = (float)(cv_hi - cv_lo);

        float res[8];
        #pragma unroll
        for (int k = 0; k < 4; ++k) {
            int i = 4*tid + k;
            int hi = i + RAD; if (hi > W-1) hi = W-1; hi = PAD(hi);
            int lo = i - RAD - 1;
            int lop = PAD(lo >= 0 ? lo : 0);
            float m = (lo >= 0) ? 1.f : 0.f;
            float bI  = s0[hi] - m*s0[lop];
            float bp  = s1[hi] - m*s1[lop];
            float bIp = s2[hi] - m*s2[lop];
            float bII = s3[hi] - m*s3[lop];
            int ch_hi = i + RAD + 1; if (ch_hi > W) ch_hi = W;
            int ch_lo = i - RAD;     if (ch_lo < 0) ch_lo = 0;
            float ic = 1.f / (cntV * (float)(ch_hi - ch_lo));
            float mI=bI*ic, mp=bp*ic, mIp=bIp*ic, mII=bII*ic;
            float cov = mIp - mI*mp;
            float var = mII - mI*mI;
            float aa = cov / (var + EPS);
            res[2*k]   = aa;
            res[2*k+1] = mp - aa*mI;
        }
        float4* abrow = (float4*)(ab + 2*(plane + (size_t)y * W));
        abrow[2*tid]   = make_float4(res[0], res[1], res[2], res[3]);
        abrow[2*tid+1] = make_float4(res[4], res[5], res[6], res[7]);

        if (ys >= 0) {
            v0[0] -= sa_.x; v0[1] -= sa_.y; v0[2] -= sa_.z; v0[3] -= sa_.w;
            v1[0] -= sb_.x; v1[1] -= sb_.y; v1[2] -= sb_.z; v1[3] -= sb_.w;
            v2[0] -= sa_.x*sb_.x; v2[1] -= sa_.y*sb_.y; v2[2] -= sa_.z*sb_.z; v2[3] -= sa_.w*sb_.w;
            v3[0] -= sa_.x*sa_.x; v3[1] -= sa_.y*sa_.y; v3[2] -= sa_.z*sa_.z; v3[3] -= sa_.w*sa_.w;
        }
        pa = na; pb = nb;
    }
}

// ---------------------------------------------------------------------------
// K_B: fused vertical slide + horizontal scan on a,b (AoS) + epilogue.
// out = mean_a * I + mean_b
// ---------------------------------------------------------------------------
__global__ __launch_bounds__(256)
void fused_out_kernel(const float* __restrict__ ab, const float* __restrict__ Iin,
                      float* __restrict__ out, int H, int W, int nstrip) {
    __shared__ float sa[1056], sb[1056];
    __shared__ float wsum[4][2];
    const int tid = threadIdx.x, lane = tid & 63, wid = tid >> 6;
    const int c = blockIdx.x / nstrip;
    const int y0 = (blockIdx.x - c * nstrip) * SEGF;
    const size_t plane = (size_t)c * H * W;

    float va[4] = {0,0,0,0}, vb[4] = {0,0,0,0};

    int yp0 = y0 - RAD; if (yp0 < 0) yp0 = 0;
    int yp1 = y0 + RAD; if (yp1 > H) yp1 = H;
    #pragma unroll 4
    for (int y = yp0; y < yp1; ++y) {
        const float4* abrow = (const float4*)(ab + 2*(plane + (size_t)y * W));
        float4 q0 = abrow[2*tid], q1 = abrow[2*tid+1];
        va[0]+=q0.x; vb[0]+=q0.y; va[1]+=q0.z; vb[1]+=q0.w;
        va[2]+=q1.x; vb[2]+=q1.y; va[3]+=q1.z; vb[3]+=q1.w;
    }

    float4 pq0, pq1;
    if (y0 + RAD < H) {
        const float4* abrow = (const float4*)(ab + 2*(plane + (size_t)(y0 + RAD) * W));
        pq0 = abrow[2*tid]; pq1 = abrow[2*tid+1];
    }

    for (int y = y0; y < y0 + SEGF; ++y) {
        if (y + RAD < H) {
            va[0]+=pq0.x; vb[0]+=pq0.y; va[1]+=pq0.z; vb[1]+=pq0.w;
            va[2]+=pq1.x; vb[2]+=pq1.y; va[3]+=pq1.z; vb[3]+=pq1.w;
        }
        const int yn = y + 1 + RAD;
        const bool nh = (yn < H) && (y + 1 < y0 + SEGF);
        float4 nq0, nq1;
        if (nh) {
            const float4* abrow = (const float4*)(ab + 2*(plane + (size_t)yn * W));
            nq0 = abrow[2*tid]; nq1 = abrow[2*tid+1];
        }
        const int ys = y - RAD;
        float4 sq0, sq1;
        if (ys >= 0) {
            const float4* abrow = (const float4*)(ab + 2*(plane + (size_t)ys * W));
            sq0 = abrow[2*tid]; sq1 = abrow[2*tid+1];
        }
        float4 Iv = ((const float4*)(Iin + plane + (size_t)y * W))[tid];

        float ca[4], cb[4];
        ca[0]=va[0]; ca[1]=ca[0]+va[1]; ca[2]=ca[1]+va[2]; ca[3]=ca[2]+va[3];
        cb[0]=vb[0]; cb[1]=cb[0]+vb[1]; cb[2]=cb[1]+vb[2]; cb[3]=cb[2]+vb[3];
        float ta=ca[3], tb=cb[3];
        float ua=ta, ub=tb;
        #pragma unroll
        for (int d = 1; d < 64; d <<= 1) {
            float na_=__shfl_up(ua,d,64), nb_=__shfl_up(ub,d,64);
            if (lane >= d) { ua+=na_; ub+=nb_; }
        }
        if (lane == 63) { wsum[wid][0]=ua; wsum[wid][1]=ub; }
        __syncthreads();
        float wa=0.f, wb=0.f;
        #pragma unroll
        for (int w = 0; w < 3; ++w)
            if (w < wid) { wa+=wsum[w][0]; wb+=wsum[w][1]; }
        float ea=wa+ua-ta, eb=wb+ub-tb;
        #pragma unroll
        for (int k = 0; k < 4; ++k) {
            int e = PAD(4*tid+k);
            sa[e]=ea+ca[k]; sb[e]=eb+cb[k];
        }
        __syncthreads();

        int cv_hi = y + RAD + 1; if (cv_hi > H) cv_hi = H;
        int cv_lo = y - RAD;     if (cv_lo < 0) cv_lo = 0;
        float cntV = (float)(cv_hi - cv_lo);

        float4 o;
        float oo[4];
        #pragma unroll
        for (int k = 0; k < 4; ++k) {
            int i = 4*tid + k;
            int hi = i + RAD; if (hi > W-1) hi = W-1; hi = PAD(hi);
            int lo = i - RAD - 1;
            int lop = PAD(lo >= 0 ? lo : 0);
            float m = (lo >= 0) ? 1.f : 0.f;
            float ba = sa[hi] - m*sa[lop];
            float bb = sb[hi] - m*sb[lop];
            int ch_hi = i + RAD + 1; if (ch_hi > W) ch_hi = W;
            int ch_lo = i - RAD;     if (ch_lo < 0) ch_lo = 0;
            float ic = 1.f / (cntV * (float)(ch_hi - ch_lo));
            float Ik = (k==0)?Iv.x:(k==1)?Iv.y:(k==2)?Iv.z:Iv.w;
            oo[k] = (ba*ic)*Ik + bb*ic;
        }
        o = make_float4(oo[0], oo[1], oo[2], oo[3]);
        ((float4*)(out + plane + (size_t)y * W))[tid] = o;

        if (ys >= 0) {
            va[0]-=sq0.x; vb[0]-=sq0.y; va[1]-=sq0.z; vb[1]-=sq0.w;
            va[2]-=sq1.x; vb[2]-=sq1.y; va[3]-=sq1.z; vb[3]-=sq1.w;
        }
        pq0 = nq0; pq1 = nq1;
    }
}

extern "C" void kernel_launch(void* const* d_in, const int* in_sizes, int n_in,
                              void* d_out, int out_size, void* d_ws, size_t ws_size,
                              hipStream_t stream) {
    const float* I = (const float*)d_in[0];
    const float* p = (const float*)d_in[1];
    float* out = (float*)d_out;

    const int H = 1024, W = 1024;
    const int N = in_sizes[0];       // B*C*H*W
    const int BC = N / (H * W);

    float* ab = (float*)d_ws;        // AoS {a,b} per pixel: 2*N floats

    const int nstrip = H / SEGF;
    fused_ab_kernel<<<dim3(BC * nstrip), 256, 0, stream>>>(I, p, ab, H, W, nstrip);
    fused_out_kernel<<<dim3(BC * nstrip), 256, 0, stream>>>(ab, I, out, H, W, nstrip);
}

// Round 4
// 301.064 us; speedup vs baseline: 1.7022x; 1.1237x over previous
//
#include <hip/hip_runtime.h>
#include <hip/hip_fp16.h>

#define RAD 40
#define SEGF 16          // output rows per wave-strip
#define TX 256           // output cols per tile
#define HH 1024
#define WW 1024
// scan domain per tile: [x0-RAD, x0+TX+RAD) = 336 cols, zero-padded to 512
// (2 chunks of 256; lane l owns cols 4l..4l+3 of each chunk)

__device__ __forceinline__ float wscan64(float v, int lane) {
    #pragma unroll
    for (int d = 1; d < 64; d <<= 1) {
        float n = __shfl_up(v, d, 64);
        if (lane >= d) v += n;
    }
    return v;
}

// ---------------------------------------------------------------------------
// K_A: one wave per (channel, x-tile, y-strip). Vertical sliding sums of
// I, p, I*p, I*I in registers; per-row chained wave-scan; writes a,b fp16x2.
// ---------------------------------------------------------------------------
__global__ __launch_bounds__(64, 3)
void fused_ab_kernel(const float* __restrict__ I, const float* __restrict__ p,
                     unsigned int* __restrict__ ab) {
    __shared__ __align__(16) float PF[4][512];
    const int l = threadIdx.x;
    const int bid = blockIdx.x;
    const int strip = bid & 63;
    const int xt = (bid >> 6) & 3;
    const int c = bid >> 8;
    const int x0 = xt * TX;
    const int y0 = strip * SEGF;
    const size_t plane = (size_t)c * (HH * WW);

    const int g1 = x0 - RAD + 4 * l;     // chunk0 col (mult of 4)
    const int g2 = g1 + 256;             // chunk1 col
    const bool v1 = (g1 >= 0) && (g1 < WW);
    const bool v2 = (l < 20) && (g2 >= 0) && (g2 < WW);

    // vertical sliding sums [field][chunk][k]: 0=I 1=p 2=Ip 3=II
    float s[4][2][4];
    #pragma unroll
    for (int f = 0; f < 4; ++f)
        #pragma unroll
        for (int ch = 0; ch < 2; ++ch)
            #pragma unroll
            for (int k = 0; k < 4; ++k) s[f][ch][k] = 0.f;

    auto load2 = [&](const float* src, int y, float* r) {
        const float* row = src + plane + (size_t)y * WW;
        float4 A = v1 ? *(const float4*)(row + g1) : make_float4(0.f,0.f,0.f,0.f);
        float4 B = v2 ? *(const float4*)(row + g2) : make_float4(0.f,0.f,0.f,0.f);
        r[0]=A.x; r[1]=A.y; r[2]=A.z; r[3]=A.w;
        r[4]=B.x; r[5]=B.y; r[6]=B.z; r[7]=B.w;
    };
    auto acc = [&](const float* ri, const float* rp, float sg) {
        #pragma unroll
        for (int j = 0; j < 8; ++j) {
            const int ch = j >> 2, k = j & 3;
            s[0][ch][k] += sg * ri[j];
            s[1][ch][k] += sg * rp[j];
            s[2][ch][k] += sg * ri[j] * rp[j];
            s[3][ch][k] += sg * ri[j] * ri[j];
        }
    };

    // prime rows [y0-RAD, y0+RAD)
    int yp0 = y0 - RAD; if (yp0 < 0) yp0 = 0;
    int yp1 = y0 + RAD; if (yp1 > HH) yp1 = HH;
    for (int y = yp0; y < yp1; ++y) {
        float ri[8], rp[8];
        load2(I, y, ri); load2(p, y, rp);
        acc(ri, rp, 1.f);
    }

    float pi[8], pp[8];
    if (y0 + RAD < HH) { load2(I, y0 + RAD, pi); load2(p, y0 + RAD, pp); }

    for (int y = y0; y < y0 + SEGF; ++y) {
        if (y + RAD < HH) acc(pi, pp, 1.f);
        // prefetch next add-row and this row's sub-row
        float ni[8], np[8], si[8], sp[8];
        const int yn = y + 1 + RAD;
        const bool nh = (yn < HH) && (y + 1 < y0 + SEGF);
        if (nh) { load2(I, yn, ni); load2(p, yn, np); }
        const int ys = y - RAD;
        if (ys >= 0) { load2(I, ys, si); load2(p, ys, sp); }

        // chained scans (chunk0 then chunk1), prefix -> LDS
        float incl0[4][4];
        #pragma unroll
        for (int f = 0; f < 4; ++f) {
            float c0 = s[f][0][0];
            float c1 = c0 + s[f][0][1];
            float c2 = c1 + s[f][0][2];
            float c3 = c2 + s[f][0][3];
            float t = wscan64(c3, l);
            float tot0 = __shfl(t, 63);
            float b0 = t - c3;
            float d0 = s[f][1][0];
            float d1 = d0 + s[f][1][1];
            float d2 = d1 + s[f][1][2];
            float d3 = d2 + s[f][1][3];
            float u = wscan64(d3, l);
            float b1 = tot0 + (u - d3);
            incl0[f][0] = b0 + c0; incl0[f][1] = b0 + c1;
            incl0[f][2] = b0 + c2; incl0[f][3] = b0 + c3;
            ((float4*)PF[f])[l]      = make_float4(incl0[f][0], incl0[f][1], incl0[f][2], incl0[f][3]);
            ((float4*)PF[f])[64 + l] = make_float4(b1 + d0, b1 + d1, b1 + d2, b1 + d3);
        }
        __syncthreads();   // single-wave workgroup: compiler fence, ~free

        int cv_hi = y + RAD + 1; if (cv_hi > HH) cv_hi = HH;
        int cv_lo = y - RAD;     if (cv_lo < 0)  cv_lo = 0;
        const float cntV = (float)(cv_hi - cv_lo);

        float4 hi0 = ((const float4*)PF[0])[l + 20];
        float4 hi1 = ((const float4*)PF[1])[l + 20];
        float4 hi2 = ((const float4*)PF[2])[l + 20];
        float4 hi3 = ((const float4*)PF[3])[l + 20];
        const float* h0 = (const float*)&hi0;
        const float* h1 = (const float*)&hi1;
        const float* h2 = (const float*)&hi2;
        const float* h3 = (const float*)&hi3;

        unsigned int outw[4];
        #pragma unroll
        for (int k = 0; k < 4; ++k) {
            const int go = x0 + 4 * l + k;
            float bI  = h0[k] - (incl0[0][k] - s[0][0][k]);
            float bp  = h1[k] - (incl0[1][k] - s[1][0][k]);
            float bIp = h2[k] - (incl0[2][k] - s[2][0][k]);
            float bII = h3[k] - (incl0[3][k] - s[3][0][k]);
            int hlo = go - RAD;     if (hlo < 0)  hlo = 0;
            int hhi = go + RAD + 1; if (hhi > WW) hhi = WW;
            const float ic = 1.f / (cntV * (float)(hhi - hlo));
            float mI = bI*ic, mp = bp*ic, mIp = bIp*ic, mII = bII*ic;
            float cov = mIp - mI * mp;
            float var = mII - mI * mI;
            float aa = cov / (var + 1e-3f);
            float bb = mp - aa * mI;
            __half2 h = __float22half2_rn(make_float2(aa, bb));
            outw[k] = *reinterpret_cast<unsigned int*>(&h);
        }
        ((uint4*)(ab + plane + (size_t)y * WW))[(x0 >> 2) + l] =
            make_uint4(outw[0], outw[1], outw[2], outw[3]);

        if (ys >= 0) acc(si, sp, -1.f);
        if (nh) {
            #pragma unroll
            for (int j = 0; j < 8; ++j) { pi[j] = ni[j]; pp[j] = np[j]; }
        }
        __syncthreads();   // protect next iter's PF writes vs this iter's reads
    }
}

// ---------------------------------------------------------------------------
// K_B: same structure on packed a,b; epilogue out = mean_a * I + mean_b
// ---------------------------------------------------------------------------
__global__ __launch_bounds__(64, 3)
void fused_out_kernel(const unsigned int* __restrict__ ab, const float* __restrict__ I,
                      float* __restrict__ out) {
    __shared__ __align__(16) float PF[2][512];
    const int l = threadIdx.x;
    const int bid = blockIdx.x;
    const int strip = bid & 63;
    const int xt = (bid >> 6) & 3;
    const int c = bid >> 8;
    const int x0 = xt * TX;
    const int y0 = strip * SEGF;
    const size_t plane = (size_t)c * (HH * WW);

    const int g1 = x0 - RAD + 4 * l;
    const int g2 = g1 + 256;
    const bool v1 = (g1 >= 0) && (g1 < WW);
    const bool v2 = (l < 20) && (g2 >= 0) && (g2 < WW);

    float s[2][2][4];
    #pragma unroll
    for (int f = 0; f < 2; ++f)
        #pragma unroll
        for (int ch = 0; ch < 2; ++ch)
            #pragma unroll
            for (int k = 0; k < 4; ++k) s[f][ch][k] = 0.f;

    auto load2u = [&](int y, float* ra, float* rb) {
        const unsigned int* row = ab + plane + (size_t)y * WW;
        uint4 A = v1 ? *(const uint4*)(row + g1) : make_uint4(0u,0u,0u,0u);
        uint4 B = v2 ? *(const uint4*)(row + g2) : make_uint4(0u,0u,0u,0u);
        const unsigned int* aw = (const unsigned int*)&A;
        const unsigned int* bw = (const unsigned int*)&B;
        #pragma unroll
        for (int k = 0; k < 4; ++k) {
            __half2 ha = *reinterpret_cast<const __half2*>(&aw[k]);
            float2 fa = __half22float2(ha);
            ra[k] = fa.x; rb[k] = fa.y;
            __half2 hb = *reinterpret_cast<const __half2*>(&bw[k]);
            float2 fb = __half22float2(hb);
            ra[4+k] = fb.x; rb[4+k] = fb.y;
        }
    };
    auto acc = [&](const float* ra, const float* rb, float sg) {
        #pragma unroll
        for (int j = 0; j < 8; ++j) {
            const int ch = j >> 2, k = j & 3;
            s[0][ch][k] += sg * ra[j];
            s[1][ch][k] += sg * rb[j];
        }
    };

    int yp0 = y0 - RAD; if (yp0 < 0) yp0 = 0;
    int yp1 = y0 + RAD; if (yp1 > HH) yp1 = HH;
    for (int y = yp0; y < yp1; ++y) {
        float ra[8], rb[8];
        load2u(y, ra, rb);
        acc(ra, rb, 1.f);
    }

    float pa[8], pb[8];
    if (y0 + RAD < HH) load2u(y0 + RAD, pa, pb);

    for (int y = y0; y < y0 + SEGF; ++y) {
        if (y + RAD < HH) acc(pa, pb, 1.f);
        float na[8], nb[8], sa[8], sb[8];
        const int yn = y + 1 + RAD;
        const bool nh = (yn < HH) && (y + 1 < y0 + SEGF);
        if (nh) load2u(yn, na, nb);
        const int ys = y - RAD;
        if (ys >= 0) load2u(ys, sa, sb);

        float incl0[2][4];
        #pragma unroll
        for (int f = 0; f < 2; ++f) {
            float c0 = s[f][0][0];
            float c1 = c0 + s[f][0][1];
            float c2 = c1 + s[f][0][2];
            float c3 = c2 + s[f][0][3];
            float t = wscan64(c3, l);
            float tot0 = __shfl(t, 63);
            float b0 = t - c3;
            float d0 = s[f][1][0];
            float d1 = d0 + s[f][1][1];
            float d2 = d1 + s[f][1][2];
            float d3 = d2 + s[f][1][3];
            float u = wscan64(d3, l);
            float b1 = tot0 + (u - d3);
            incl0[f][0] = b0 + c0; incl0[f][1] = b0 + c1;
            incl0[f][2] = b0 + c2; incl0[f][3] = b0 + c3;
            ((float4*)PF[f])[l]      = make_float4(incl0[f][0], incl0[f][1], incl0[f][2], incl0[f][3]);
            ((float4*)PF[f])[64 + l] = make_float4(b1 + d0, b1 + d1, b1 + d2, b1 + d3);
        }
        __syncthreads();

        int cv_hi = y + RAD + 1; if (cv_hi > HH) cv_hi = HH;
        int cv_lo = y - RAD;     if (cv_lo < 0)  cv_lo = 0;
        const float cntV = (float)(cv_hi - cv_lo);

        float4 hiA = ((const float4*)PF[0])[l + 20];
        float4 hiB = ((const float4*)PF[1])[l + 20];
        const float* hA = (const float*)&hiA;
        const float* hB = (const float*)&hiB;
        float4 Iv = ((const float4*)(I + plane + (size_t)y * WW))[(x0 >> 2) + l];
        const float* Ik = (const float*)&Iv;

        float oo[4];
        #pragma unroll
        for (int k = 0; k < 4; ++k) {
            const int go = x0 + 4 * l + k;
            float ba = hA[k] - (incl0[0][k] - s[0][0][k]);
            float bb = hB[k] - (incl0[1][k] - s[1][0][k]);
            int hlo = go - RAD;     if (hlo < 0)  hlo = 0;
            int hhi = go + RAD + 1; if (hhi > WW) hhi = WW;
            const float ic = 1.f / (cntV * (float)(hhi - hlo));
            oo[k] = (ba * ic) * Ik[k] + bb * ic;
        }
        ((float4*)(out + plane + (size_t)y * WW))[(x0 >> 2) + l] =
            make_float4(oo[0], oo[1], oo[2], oo[3]);

        if (ys >= 0) acc(sa, sb, -1.f);
        if (nh) {
            #pragma unroll
            for (int j = 0; j < 8; ++j) { pa[j] = na[j]; pb[j] = nb[j]; }
        }
        __syncthreads();
    }
}

extern "C" void kernel_launch(void* const* d_in, const int* in_sizes, int n_in,
                              void* d_out, int out_size, void* d_ws, size_t ws_size,
                              hipStream_t stream) {
    const float* I = (const float*)d_in[0];
    const float* p = (const float*)d_in[1];
    float* out = (float*)d_out;

    const int N = in_sizes[0];           // B*C*H*W
    const int BC = N / (HH * WW);

    unsigned int* ab = (unsigned int*)d_ws;   // fp16x2 {a,b} per pixel

    const int nblk = BC * (WW / TX) * (HH / SEGF);   // BC * 4 * 64
    fused_ab_kernel<<<dim3(nblk), 64, 0, stream>>>(I, p, ab);
    fused_out_kernel<<<dim3(nblk), 64, 0, stream>>>(ab, I, out);
}